// Round 1
// baseline (509.305 us; speedup 1.0000x reference)
//
#include <hip/hip_runtime.h>
#include <hip/hip_bf16.h>

#define BB 64
#define SS 4096
#define HH 256
#define AA 128
#define MT 128
#define BK 32

__device__ __forceinline__ float fast_tanh(float x) {
    float xc = fminf(fmaxf(x, -9.0f), 9.0f);
    float e = __expf(2.0f * xc);
    return 1.0f - __fdividef(2.0f, e + 1.0f);
}

// ---------------------------------------------------------------------------
// K1: scores[m] = tanh(X[m,:]@W1 + b1) @ W2 + b2   for m in [0, B*S)
// fp32 register-tiled GEMM, 128 rows x 128 cols per block, fused epilogue.
// ---------------------------------------------------------------------------
__global__ __launch_bounds__(256) void score_kernel(
    const float* __restrict__ X,   // [B*S, H]
    const float* __restrict__ W1,  // [H, A]
    const float* __restrict__ b1,  // [A]
    const float* __restrict__ W2,  // [A]
    const float* __restrict__ b2,  // [1]
    float* __restrict__ scores)    // [B*S]
{
    __shared__ float Xs[BK][MT + 4];   // [k][m] (transposed)
    __shared__ float Ws[BK][AA + 4];   // [k][n]

    const int tid = threadIdx.x;
    const int m0  = blockIdx.x * MT;
    const int tx  = tid & 15;    // n-group: cols tx*8 .. tx*8+7
    const int ty  = tid >> 4;    // m-group: rows ty*8 .. ty*8+7

    float acc[8][8];
    #pragma unroll
    for (int i = 0; i < 8; ++i)
        #pragma unroll
        for (int j = 0; j < 8; ++j) acc[i][j] = 0.0f;

    const int xr = tid >> 3;          // 0..31
    const int xc = (tid & 7) * 4;     // 0..28
    const int wk = tid >> 5;          // 0..7
    const int wc = (tid & 31) * 4;    // 0..124

    for (int k0 = 0; k0 < HH; k0 += BK) {
        #pragma unroll
        for (int i = 0; i < 4; ++i) {
            int row = xr + i * 32;
            float4 v = *(const float4*)(X + (size_t)(m0 + row) * HH + k0 + xc);
            Xs[xc + 0][row] = v.x;
            Xs[xc + 1][row] = v.y;
            Xs[xc + 2][row] = v.z;
            Xs[xc + 3][row] = v.w;
        }
        #pragma unroll
        for (int i = 0; i < 4; ++i) {
            int k = wk + i * 8;
            *(float4*)&Ws[k][wc] = *(const float4*)(W1 + (size_t)(k0 + k) * AA + wc);
        }
        __syncthreads();
        #pragma unroll
        for (int k = 0; k < BK; ++k) {
            float a[8], bb[8];
            *(float4*)&a[0]  = *(const float4*)&Xs[k][ty * 8];
            *(float4*)&a[4]  = *(const float4*)&Xs[k][ty * 8 + 4];
            *(float4*)&bb[0] = *(const float4*)&Ws[k][tx * 8];
            *(float4*)&bb[4] = *(const float4*)&Ws[k][tx * 8 + 4];
            #pragma unroll
            for (int i = 0; i < 8; ++i)
                #pragma unroll
                for (int j = 0; j < 8; ++j)
                    acc[i][j] = fmaf(a[i], bb[j], acc[i][j]);
        }
        __syncthreads();
    }

    // epilogue: tanh + dot with W2, reduce across the 16 column-groups
    const int c = tx * 8;
    float w2r[8], b1r[8];
    #pragma unroll
    for (int j = 0; j < 8; ++j) { w2r[j] = W2[c + j]; b1r[j] = b1[c + j]; }

    float* red = &Xs[0][0];  // reuse: 128*17 = 2176 <= 32*132 = 4224 floats
    #pragma unroll
    for (int i = 0; i < 8; ++i) {
        float p = 0.0f;
        #pragma unroll
        for (int j = 0; j < 8; ++j)
            p += fast_tanh(acc[i][j] + b1r[j]) * w2r[j];
        red[(ty * 8 + i) * 17 + tx] = p;
    }
    __syncthreads();
    if (tid < MT) {
        float s = b2[0];
        #pragma unroll
        for (int t = 0; t < 16; ++t) s += red[tid * 17 + t];
        scores[m0 + tid] = s;
    }
}

// ---------------------------------------------------------------------------
// K2: entmax-1.5 over S per batch row, via bisection on tau:
//   z = scores/2 - max;  find tau with sum((z-tau)_+^2) = 1;  w = (z-tau)_+^2
// In-place: buf holds scores on entry, weights on exit. Also zeros context.
// ---------------------------------------------------------------------------
__global__ __launch_bounds__(256) void entmax_kernel(
    float* __restrict__ buf,   // [B, S] scores -> weights (d_out weights region)
    float* __restrict__ ctx)   // [B, H]  zero-initialized here
{
    __shared__ float sred[4];
    const int b = blockIdx.x, tid = threadIdx.x;
    float* p = buf + (size_t)b * SS;

    float z[16];
    #pragma unroll
    for (int j = 0; j < 16; ++j) z[j] = p[tid + j * 256] * 0.5f;

    // block max
    float m = -1e30f;
    #pragma unroll
    for (int j = 0; j < 16; ++j) m = fmaxf(m, z[j]);
    #pragma unroll
    for (int o = 1; o < 64; o <<= 1) m = fmaxf(m, __shfl_xor(m, o));
    if ((tid & 63) == 0) sred[tid >> 6] = m;
    __syncthreads();
    m = fmaxf(fmaxf(sred[0], sred[1]), fmaxf(sred[2], sred[3]));
    __syncthreads();
    #pragma unroll
    for (int j = 0; j < 16; ++j) z[j] -= m;

    // bisection: f(lo=-1) >= 1 (max term alone = 1), f(hi=0) = 0
    float lo = -1.0f, hi = 0.0f;
    for (int it = 0; it < 35; ++it) {
        float tau = 0.5f * (lo + hi);
        float s = 0.0f;
        #pragma unroll
        for (int j = 0; j < 16; ++j) {
            float d = fmaxf(z[j] - tau, 0.0f);
            s = fmaf(d, d, s);
        }
        #pragma unroll
        for (int o = 1; o < 64; o <<= 1) s += __shfl_xor(s, o);
        if ((tid & 63) == 0) sred[tid >> 6] = s;
        __syncthreads();
        s = sred[0] + sred[1] + sred[2] + sred[3];
        __syncthreads();
        if (s >= 1.0f) lo = tau; else hi = tau;
    }
    const float tau = 0.5f * (lo + hi);

    #pragma unroll
    for (int j = 0; j < 16; ++j) {
        float d = fmaxf(z[j] - tau, 0.0f);
        p[tid + j * 256] = d * d;
    }
    ctx[b * HH + tid] = 0.0f;  // 256 threads == H entries per batch
}

// ---------------------------------------------------------------------------
// K3: context[b,h] += sum_s X[b,s,h] * w[b,s], chunked over s with zero-skip
// (entmax weights are sparse: ~40-60 nonzero of 4096 -> skip ~97% of X reads)
// ---------------------------------------------------------------------------
__global__ __launch_bounds__(256) void context_kernel(
    const float* __restrict__ X,   // [B, S, H]
    const float* __restrict__ w,   // [B, S]
    float* __restrict__ ctx)       // [B, H]
{
    const int b  = blockIdx.y;
    const int s0 = blockIdx.x * 128;
    const int h  = threadIdx.x;

    __shared__ float ws_[128];
    __shared__ int nzflag;
    if (h == 0) nzflag = 0;
    __syncthreads();
    if (h < 128) {
        float v = w[(size_t)b * SS + s0 + h];
        ws_[h] = v;
        if (v > 0.0f) nzflag = 1;  // benign race: all writers store 1
    }
    __syncthreads();
    if (!nzflag) return;

    float acc = 0.0f;
    const float* xp = X + ((size_t)b * SS + s0) * HH + h;
    #pragma unroll 4
    for (int i = 0; i < 128; ++i) {
        float wv = ws_[i];
        if (wv != 0.0f) acc = fmaf(xp[(size_t)i * HH], wv, acc);
    }
    atomicAdd(&ctx[b * HH + h], acc);
}

extern "C" void kernel_launch(void* const* d_in, const int* in_sizes, int n_in,
                              void* d_out, int out_size, void* d_ws, size_t ws_size,
                              hipStream_t stream) {
    const float* X  = (const float*)d_in[0];   // [64, 4096, 256]
    const float* W1 = (const float*)d_in[1];   // [256, 128]
    const float* b1 = (const float*)d_in[2];   // [128]
    const float* W2 = (const float*)d_in[3];   // [128, 1]
    const float* b2 = (const float*)d_in[4];   // [1]

    float* out = (float*)d_out;
    float* ctx = out;            // [64*256]
    float* wts = out + BB * HH;  // [64*4096] — holds scores between K1 and K2

    score_kernel<<<(BB * SS) / MT, 256, 0, stream>>>(X, W1, b1, W2, b2, wts);
    entmax_kernel<<<BB, 256, 0, stream>>>(wts, ctx);
    context_kernel<<<dim3(SS / 128, BB), 256, 0, stream>>>(X, wts, ctx);
}

// Round 2
// 401.369 us; speedup vs baseline: 1.2689x; 1.2689x over previous
//
#include <hip/hip_runtime.h>
#include <hip/hip_bf16.h>

#define BB 64
#define SS 4096
#define HH 256
#define AA 128
#define MT 128      // M tile per block
#define BK 64       // K chunk
#define XST 72      // LDS row stride in f16 (64 + 8 pad -> 144 B, 16B aligned)

typedef _Float16 half4v __attribute__((ext_vector_type(4)));
typedef _Float16 half8v __attribute__((ext_vector_type(8)));
typedef float floatx16 __attribute__((ext_vector_type(16)));

__device__ __forceinline__ float fast_tanh(float x) {
    float xc = fminf(fmaxf(x, -9.0f), 9.0f);
    float e = __expf(2.0f * xc);
    return 1.0f - __fdividef(2.0f, e + 1.0f);
}

// ---------------------------------------------------------------------------
// K0: W1 [H=256][A=128] fp32  ->  Wt [A=128][H=256] f16 (transposed) in d_ws
// ---------------------------------------------------------------------------
__global__ void convert_w1(const float* __restrict__ W1, _Float16* __restrict__ Wt) {
    int n = blockIdx.x;    // 0..127 (A)
    int k = threadIdx.x;   // 0..255 (H)
    Wt[n * HH + k] = (_Float16)W1[k * AA + n];
}

// ---------------------------------------------------------------------------
// K1: scores[m] = tanh(X[m,:]@W1 + b1) @ W2 + b2  via f16 MFMA (fp32 accum)
// Block: 256 thr (4 waves), tile M=128 x N=128, K-loop BK=64.
// Wave w: rows (w&1)*64 .. +63, cols (w>>1)*64 .. +63 as 2x2 tiles of 32x32.
// ---------------------------------------------------------------------------
__global__ __launch_bounds__(256) void score_mfma(
    const float* __restrict__ X,        // [B*S, H]
    const _Float16* __restrict__ Wt,    // [A, H] f16 (W1 transposed)
    const float* __restrict__ b1,       // [A]
    const float* __restrict__ W2,       // [A]
    const float* __restrict__ b2,       // [1]
    float* __restrict__ scores)         // [B*S]
{
    __shared__ float smem_f[9216];                       // 36864 B
    _Float16* Xs = (_Float16*)smem_f;                    // [128][XST]
    _Float16* Ws = (_Float16*)smem_f + MT * XST;         // [128][XST]
    float* part = smem_f;                                // [128][65] epilogue reuse

    const int tid   = threadIdx.x;
    const int m0    = blockIdx.x * MT;
    const int wid   = tid >> 6;
    const int lane  = tid & 63;
    const int lrow  = lane & 31;
    const int lhalf = lane >> 5;
    const int wr    = (wid & 1) * 64;
    const int wc    = (wid >> 1) * 64;

    floatx16 acc[2][2];
    #pragma unroll
    for (int i = 0; i < 2; ++i)
        #pragma unroll
        for (int j = 0; j < 2; ++j)
            #pragma unroll
            for (int r = 0; r < 16; ++r) acc[i][j][r] = 0.0f;

    for (int k0 = 0; k0 < HH; k0 += BK) {
        // --- stage X chunk: 128 rows x 64 k fp32 -> f16 LDS (cvt in regs) ---
        #pragma unroll
        for (int p = 0; p < 8; ++p) {
            int idx = tid + p * 256;
            int row = idx >> 4, c4 = idx & 15;
            float4 v = *(const float4*)(X + (size_t)(m0 + row) * HH + k0 + c4 * 4);
            half4v hv;
            hv[0] = (_Float16)v.x; hv[1] = (_Float16)v.y;
            hv[2] = (_Float16)v.z; hv[3] = (_Float16)v.w;
            *(half4v*)(Xs + row * XST + c4 * 4) = hv;
        }
        // --- stage Wt chunk: 128 n-rows x 64 k f16, 16B vector loads ---
        #pragma unroll
        for (int p = 0; p < 4; ++p) {
            int idx = tid + p * 256;
            int n = idx >> 3, u = idx & 7;
            uint4 v = *(const uint4*)(Wt + (size_t)n * HH + k0 + u * 8);
            *(uint4*)(Ws + n * XST + u * 8) = v;
        }
        __syncthreads();
        // --- MFMA inner loop ---
        #pragma unroll
        for (int kk = 0; kk < BK; kk += 16) {
            half8v a0 = *(half8v*)(Xs + (wr + lrow) * XST + kk + lhalf * 8);
            half8v a1 = *(half8v*)(Xs + (wr + 32 + lrow) * XST + kk + lhalf * 8);
            half8v b0 = *(half8v*)(Ws + (wc + lrow) * XST + kk + lhalf * 8);
            half8v bq = *(half8v*)(Ws + (wc + 32 + lrow) * XST + kk + lhalf * 8);
            acc[0][0] = __builtin_amdgcn_mfma_f32_32x32x16_f16(a0, b0, acc[0][0], 0, 0, 0);
            acc[0][1] = __builtin_amdgcn_mfma_f32_32x32x16_f16(a0, bq, acc[0][1], 0, 0, 0);
            acc[1][0] = __builtin_amdgcn_mfma_f32_32x32x16_f16(a1, b0, acc[1][0], 0, 0, 0);
            acc[1][1] = __builtin_amdgcn_mfma_f32_32x32x16_f16(a1, bq, acc[1][1], 0, 0, 0);
        }
        __syncthreads();
    }

    // --- epilogue: tanh + dot(W2), per-row partials to LDS, then reduce ---
    const int cA = wc + lrow;
    const int cB = wc + 32 + lrow;
    const float b1A = b1[cA], b1B = b1[cB];
    const float w2A = W2[cA], w2B = W2[cB];
    #pragma unroll
    for (int i = 0; i < 2; ++i) {
        #pragma unroll
        for (int r = 0; r < 16; ++r) {
            float hA = fast_tanh(acc[i][0][r] + b1A) * w2A;
            float hB = fast_tanh(acc[i][1][r] + b1B) * w2B;
            int row = wr + i * 32 + (r & 3) + 8 * (r >> 2) + 4 * lhalf;
            part[row * 65 + (wid >> 1) * 32 + lrow] = hA + hB;
        }
    }
    __syncthreads();
    if (tid < MT) {
        float s = b2[0];
        #pragma unroll
        for (int c = 0; c < 64; ++c) s += part[tid * 65 + c];
        scores[m0 + tid] = s;
    }
}

// ---------------------------------------------------------------------------
// K2: entmax-1.5 over S per batch row via bisection on tau.
// In-place scores -> weights; zero-inits ctx.
// ---------------------------------------------------------------------------
__global__ __launch_bounds__(256) void entmax_kernel(
    float* __restrict__ buf, float* __restrict__ ctx)
{
    __shared__ float sred[4];
    const int b = blockIdx.x, tid = threadIdx.x;
    float* p = buf + (size_t)b * SS;

    float z[16];
    #pragma unroll
    for (int j = 0; j < 16; ++j) z[j] = p[tid + j * 256] * 0.5f;

    float m = -1e30f;
    #pragma unroll
    for (int j = 0; j < 16; ++j) m = fmaxf(m, z[j]);
    #pragma unroll
    for (int o = 1; o < 64; o <<= 1) m = fmaxf(m, __shfl_xor(m, o));
    if ((tid & 63) == 0) sred[tid >> 6] = m;
    __syncthreads();
    m = fmaxf(fmaxf(sred[0], sred[1]), fmaxf(sred[2], sred[3]));
    __syncthreads();
    #pragma unroll
    for (int j = 0; j < 16; ++j) z[j] -= m;

    float lo = -1.0f, hi = 0.0f;
    for (int it = 0; it < 35; ++it) {
        float tau = 0.5f * (lo + hi);
        float s = 0.0f;
        #pragma unroll
        for (int j = 0; j < 16; ++j) {
            float d = fmaxf(z[j] - tau, 0.0f);
            s = fmaf(d, d, s);
        }
        #pragma unroll
        for (int o = 1; o < 64; o <<= 1) s += __shfl_xor(s, o);
        if ((tid & 63) == 0) sred[tid >> 6] = s;
        __syncthreads();
        s = sred[0] + sred[1] + sred[2] + sred[3];
        __syncthreads();
        if (s >= 1.0f) lo = tau; else hi = tau;
    }
    const float tau = 0.5f * (lo + hi);

    #pragma unroll
    for (int j = 0; j < 16; ++j) {
        float d = fmaxf(z[j] - tau, 0.0f);
        p[tid + j * 256] = d * d;
    }
    ctx[b * HH + tid] = 0.0f;
}

// ---------------------------------------------------------------------------
// K3: context[b,h] += sum_s X[b,s,h] * w[b,s]; entmax sparsity -> skip zeros
// ---------------------------------------------------------------------------
__global__ __launch_bounds__(256) void context_kernel(
    const float* __restrict__ X, const float* __restrict__ w,
    float* __restrict__ ctx)
{
    const int b  = blockIdx.y;
    const int s0 = blockIdx.x * 128;
    const int h  = threadIdx.x;

    __shared__ float ws_[128];
    __shared__ int nzflag;
    if (h == 0) nzflag = 0;
    __syncthreads();
    if (h < 128) {
        float v = w[(size_t)b * SS + s0 + h];
        ws_[h] = v;
        if (v > 0.0f) nzflag = 1;
    }
    __syncthreads();
    if (!nzflag) return;

    float acc = 0.0f;
    const float* xp = X + ((size_t)b * SS + s0) * HH + h;
    #pragma unroll 4
    for (int i = 0; i < 128; ++i) {
        float wv = ws_[i];
        if (wv != 0.0f) acc = fmaf(xp[(size_t)i * HH], wv, acc);
    }
    atomicAdd(&ctx[b * HH + h], acc);
}

extern "C" void kernel_launch(void* const* d_in, const int* in_sizes, int n_in,
                              void* d_out, int out_size, void* d_ws, size_t ws_size,
                              hipStream_t stream) {
    const float* X  = (const float*)d_in[0];
    const float* W1 = (const float*)d_in[1];
    const float* b1 = (const float*)d_in[2];
    const float* W2 = (const float*)d_in[3];
    const float* b2 = (const float*)d_in[4];

    float* out = (float*)d_out;
    float* ctx = out;            // [64*256]
    float* wts = out + BB * HH;  // [64*4096] scores -> weights
    _Float16* Wt = (_Float16*)d_ws;  // [128][256] f16, 64 KB

    convert_w1<<<AA, HH, 0, stream>>>(W1, Wt);
    score_mfma<<<(BB * SS) / MT, 256, 0, stream>>>(X, Wt, b1, W2, b2, wts);
    entmax_kernel<<<BB, 256, 0, stream>>>(wts, ctx);
    context_kernel<<<dim3(SS / 128, BB), 256, 0, stream>>>(X, wts, ctx);
}